// Round 12
// baseline (336.279 us; speedup 1.0000x reference)
//
#include <hip/hip_runtime.h>
#include <hip/hip_bf16.h>
#include <math.h>

#define B 2
#define S 2048
#define D 1024
#define H 16
#define DK 64

typedef __attribute__((ext_vector_type(8))) short bf8;            // 8 bf16 (MFMA frag)
typedef __attribute__((ext_vector_type(8))) unsigned short u16x8;
typedef __attribute__((ext_vector_type(4))) unsigned short u16x4;
typedef __attribute__((ext_vector_type(4))) float f32x4;
typedef unsigned short ush;

__device__ __forceinline__ float bf2f(ush u) {
    union { unsigned int i; float f; } v; v.i = ((unsigned int)u) << 16; return v.f;
}
__device__ __forceinline__ ush f2bf_rne(float x) {
    __hip_bfloat16 h = __float2bfloat16(x);
    union { __hip_bfloat16 h; ush u; } v; v.h = h; return v.u;
}
__device__ __forceinline__ ush f2bf_trunc(float x) {
    union { float f; unsigned int i; } v; v.f = x; return (ush)(v.i >> 16);
}

// async global->LDS, 16B per lane. LDS dest = wave-uniform base + lane*16.
__device__ __forceinline__ void gl16(const void* g, void* l) {
    __builtin_amdgcn_global_load_lds(
        (const __attribute__((address_space(1))) void*)g,
        (__attribute__((address_space(3))) void*)l, 16, 0, 0);
}

#define FENCE()    asm volatile("" ::: "memory")
#define WAIT_VM(N) asm volatile("s_waitcnt vmcnt(" #N ")" ::: "memory")
#define BARRAW()   __builtin_amdgcn_s_barrier()

// ---------------------------------------------------------------------------
// Merged pre-convert: up to 7 segments
// (query/w_q/key/w_k split; value/w_v hi-only; optional w_o hi-only)
// ---------------------------------------------------------------------------
__global__ __launch_bounds__(256) void conv_sev_k(
    const float* __restrict__ q,  ush* __restrict__ qh,  ush* __restrict__ qlo,
    const float* __restrict__ wq, ush* __restrict__ wqh, ush* __restrict__ wql,
    const float* __restrict__ k,  ush* __restrict__ kh,  ush* __restrict__ klo,
    const float* __restrict__ wk, ush* __restrict__ wkh, ush* __restrict__ wkl,
    const float* __restrict__ v,  ush* __restrict__ vh,
    const float* __restrict__ wv, ush* __restrict__ wvh,
    const float* __restrict__ wo, ush* __restrict__ woh,
    int nbX, int nbW)
{
    int bx = blockIdx.x;
    const float* src; ush* oh; ush* ol;
    if (bx < nbX) { src = q; oh = qh; ol = qlo; }
    else { bx -= nbX;
      if (bx < nbW) { src = wq; oh = wqh; ol = wql; }
      else { bx -= nbW;
        if (bx < nbX) { src = k; oh = kh; ol = klo; }
        else { bx -= nbX;
          if (bx < nbW) { src = wk; oh = wkh; ol = wkl; }
          else { bx -= nbW;
            if (bx < nbX) { src = v; oh = vh; ol = nullptr; }
            else { bx -= nbX;
              if (bx < nbW) { src = wv; oh = wvh; ol = nullptr; }
              else { bx -= nbW; src = wo; oh = woh; ol = nullptr; }
            } } } } }
    const size_t t = (size_t)bx * 256 + threadIdx.x;

    const float4* s4 = (const float4*)src + t * 2;
    float4 a = s4[0], c = s4[1];
    float vv[8] = {a.x, a.y, a.z, a.w, c.x, c.y, c.z, c.w};
    u16x8 hi;
#pragma unroll
    for (int j = 0; j < 8; ++j) hi[j] = f2bf_trunc(vv[j]);
    *(u16x8*)&oh[t * 8] = hi;
    if (ol) {
        u16x8 lo;
#pragma unroll
        for (int j = 0; j < 8; ++j) lo[j] = f2bf_rne(vv[j] - bf2f(hi[j]));
        *(u16x8*)&ol[t * 8] = lo;
    }
}

// single-tensor hi-only convert (fallback path for w_o)
__global__ __launch_bounds__(256) void conv_hi_k(
    const float* __restrict__ X, ush* __restrict__ Oh)
{
    const size_t t = (size_t)blockIdx.x * 256 + threadIdx.x;
    const float4* s4 = (const float4*)X + t * 2;
    float4 a = s4[0], c = s4[1];
    float v[8] = {a.x, a.y, a.z, a.w, c.x, c.y, c.z, c.w};
    u16x8 hi;
#pragma unroll
    for (int j = 0; j < 8; ++j) hi[j] = f2bf_trunc(v[j]);
    *(u16x8*)&Oh[t * 8] = hi;
}

// ---------------------------------------------------------------------------
// MFMA GEMM body v2 (round-10 proven): 128n x 64m tile, 256 thr / 4 waves,
// 3 LDS buffers (72 KB -> 2 blocks/CU), 2-deep counted-vmcnt (WAIT_VM(6)).
// EPI 0: fp32+bias(nt)  EPI 1: hi/lo pair  EPI 2: transposed bf16 [B][D][S]
// ---------------------------------------------------------------------------
template<bool SPLIT, int EPI>
__device__ __forceinline__ void gemm_body2(
    const ush* __restrict__ Xh, const ush* __restrict__ Xl,
    const ush* __restrict__ Wh, const ush* __restrict__ Wl,
    const float* __restrict__ bias, void* __restrict__ Y0v, void* __restrict__ Y1v,
    ush* BufS)
{
    const int tid  = threadIdx.x;
    const int lane = tid & 63;
    const int w    = tid >> 6;                 // 0..3
    const int wn   = w >> 1, wm = w & 1;
    const int m0   = blockIdx.x * 64;
    const int n0   = blockIdx.y * 128;

    f32x4 acc[4][2];
#pragma unroll
    for (int s = 0; s < 4; ++s)
#pragma unroll
        for (int t = 0; t < 2; ++t) acc[s][t] = (f32x4){0.f, 0.f, 0.f, 0.f};

    const int kg = (lane >> 4) * 8;
    const int rb = lane >> 3;                  // 0..7
    const int jd = lane & 7;
    const int kS = SPLIT ? 32 : 16;

    auto stage = [&](ush* buf, int ks) {
#pragma unroll
        for (int i = 0; i < 6; ++i) {
            int rd = w * 48 + i * 8 + rb;      // 0..191
            int jo = jd ^ (rd & 7);
            const ush* src;
            if (rd < 128) {                    // X row
                if (SPLIT)
                    src = (jo < 4) ? Xh + (size_t)(n0 + rd) * 1024 + ks * 32 + jo * 8
                                   : Xl + (size_t)(n0 + rd) * 1024 + ks * 32 + (jo - 4) * 8;
                else
                    src = Xh + (size_t)(n0 + rd) * 1024 + ks * 64 + jo * 8;
            } else {                           // W row
                int rw = rd - 128;
                if (SPLIT)
                    src = (jo < 4) ? Wh + (size_t)(m0 + rw) * 1024 + ks * 32 + jo * 8
                                   : Wl + (size_t)(m0 + rw) * 1024 + ks * 32 + (jo - 4) * 8;
                else
                    src = Wh + (size_t)(m0 + rw) * 1024 + ks * 64 + jo * 8;
            }
            gl16(src, &buf[(w * 48 + i * 8) * 64]);
        }
    };

    auto step = [&](const ush* buf) {
        bf8 a0[4], a1[4], b0[2], b1[2];
#pragma unroll
        for (int s = 0; s < 4; ++s) {
            int r = wn * 64 + s * 16 + (lane & 15);
            a0[s] = *(const bf8*)&buf[r * 64 + (kg ^ ((r & 7) << 3))];
            a1[s] = *(const bf8*)&buf[r * 64 + ((32 + kg) ^ ((r & 7) << 3))];
        }
#pragma unroll
        for (int t = 0; t < 2; ++t) {
            int r = wm * 32 + t * 16 + (lane & 15);
            b0[t] = *(const bf8*)&buf[(128 + r) * 64 + (kg ^ ((r & 7) << 3))];
            b1[t] = *(const bf8*)&buf[(128 + r) * 64 + ((32 + kg) ^ ((r & 7) << 3))];
        }
#pragma unroll
        for (int s = 0; s < 4; ++s)
#pragma unroll
            for (int t = 0; t < 2; ++t) {
                acc[s][t] = __builtin_amdgcn_mfma_f32_16x16x32_bf16(a0[s], b0[t], acc[s][t], 0, 0, 0);
                if (SPLIT) {
                    acc[s][t] = __builtin_amdgcn_mfma_f32_16x16x32_bf16(a0[s], b1[t], acc[s][t], 0, 0, 0);
                    acc[s][t] = __builtin_amdgcn_mfma_f32_16x16x32_bf16(a1[s], b0[t], acc[s][t], 0, 0, 0);
                } else {
                    acc[s][t] = __builtin_amdgcn_mfma_f32_16x16x32_bf16(a1[s], b1[t], acc[s][t], 0, 0, 0);
                }
            }
    };

    stage(&BufS[0 * 12288], 0);
    stage(&BufS[1 * 12288], 1);
    FENCE();
    WAIT_VM(6); BARRAW(); FENCE();

    for (int kt = 0; kt < kS; ++kt) {
        const int pf = kt + 2;
        if (pf < kS) { stage(&BufS[(pf % 3) * 12288], pf); FENCE(); }
        step(&BufS[(kt % 3) * 12288]);
        if (kt + 2 < kS)      { WAIT_VM(6); }
        else if (kt + 1 < kS) { WAIT_VM(0); }
        BARRAW(); FENCE();
    }

#pragma unroll
    for (int s = 0; s < 4; ++s)
#pragma unroll
        for (int t = 0; t < 2; ++t) {
            const int nb = n0 + wn * 64 + 16 * s + 4 * (lane >> 4);
            const int m  = m0 + wm * 32 + 16 * t + (lane & 15);
            if (EPI == 0) {
                float* Y = (float*)Y0v;
                const float bb = bias[m];
#pragma unroll
                for (int r = 0; r < 4; ++r)
                    __builtin_nontemporal_store(acc[s][t][r] + bb,
                                                &Y[(size_t)(nb + r) * 1024 + m]);
            } else if (EPI == 1) {
                ush* Yh = (ush*)Y0v;
                ush* Yl = (ush*)Y1v;
#pragma unroll
                for (int r = 0; r < 4; ++r) {
                    float v = acc[s][t][r];
                    ush hi = f2bf_trunc(v);
                    Yh[(size_t)(nb + r) * 1024 + m] = hi;
                    Yl[(size_t)(nb + r) * 1024 + m] = f2bf_rne(v - bf2f(hi));
                }
            } else {
                ush* Vt = (ush*)Y0v;
                u16x4 pk;
#pragma unroll
                for (int r = 0; r < 4; ++r) pk[r] = f2bf_rne(acc[s][t][r]);
                size_t addr = ((size_t)(nb >> 11) * 1024 + m) * 2048 + (nb & 2047);
                *(u16x4*)&Vt[addr] = pk;
            }
        }
}

// merged Q/K/V projection launch: z selects the GEMM
__global__ __launch_bounds__(256) void gemm_proj3(
    const ush* __restrict__ qXh, const ush* __restrict__ qXl,
    const ush* __restrict__ wqH, const ush* __restrict__ wqL,
    ush* __restrict__ Qh, ush* __restrict__ Ql,
    const ush* __restrict__ kXh, const ush* __restrict__ kXl,
    const ush* __restrict__ wkH, const ush* __restrict__ wkL,
    ush* __restrict__ Kh, ush* __restrict__ Kl,
    const ush* __restrict__ vXh, const ush* __restrict__ wvH,
    ush* __restrict__ Vt)
{
    __shared__ __align__(16) ush BufS[3 * 192 * 64];   // 72 KB
    const int z = blockIdx.z;
    if (z == 0)      gemm_body2<true, 1>(qXh, qXl, wqH, wqL, nullptr, Qh, Ql, BufS);
    else if (z == 1) gemm_body2<true, 1>(kXh, kXl, wkH, wkL, nullptr, Kh, Kl, BufS);
    else             gemm_body2<false, 2>(vXh, nullptr, wvH, nullptr, nullptr, Vt, nullptr, BufS);
}

// out-projection: fp32 + bias epilogue (nontemporal)
__global__ __launch_bounds__(256) void gemm_outk(
    const ush* __restrict__ Xh, const ush* __restrict__ Wh,
    const float* __restrict__ bias, float* __restrict__ Y)
{
    __shared__ __align__(16) ush BufS[3 * 192 * 64];   // 72 KB
    gemm_body2<false, 0>(Xh, nullptr, Wh, nullptr, bias, Y, nullptr, BufS);
}

// ---------------------------------------------------------------------------
// Attention v5 per (b, h, 256-q-tile): 256 blocks (1/CU, single round),
// 512 thr / 8 waves; each wave owns TWO 16-row q-groups processed
// sequentially per k-tile -> 2x work between each barrier pair, half the
// total staging/barrier events vs v4. Per-row math bit-identical to v4.
// XCD swizzle groups each (b,h)'s 8 q-blocks on one XCD (K/V L2-resident).
// Pass A: 3-deep Kh pipeline vmcnt(1). Pass B: 2-deep, WAIT_VM(8) leaves
// the 8 nt attn stores in flight.
// ---------------------------------------------------------------------------
__global__ __launch_bounds__(512) void attn_mfma5(
    const ush* __restrict__ Qh, const ush* __restrict__ Ql,
    const ush* __restrict__ Kh, const ush* __restrict__ Kl,
    const ush* __restrict__ Vt, const int* __restrict__ maskg,
    float* __restrict__ attn, ush* __restrict__ ctx)
{
    const int tid  = threadIdx.x;
    const int lane = tid & 63;
    const int w    = tid >> 6;                 // 0..7
    const int lid  = blockIdx.x + (blockIdx.y << 3) + (blockIdx.z << 7);
    const int swz  = ((lid & 7) << 5) | (lid >> 3);   // XCD: 4 heads, 8 q-tiles
    const int qt = swz & 7, h = (swz >> 3) & 15, b = swz >> 7;
    const int q0 = qt * 256;

    __shared__ __align__(16) ush KhsD[3][4096];
    __shared__ __align__(16) ush KlsD[2][4096];
    __shared__ __align__(16) ush VtsD[2][4096];
    __shared__ __align__(16) ush Pus[8][1024];
    __shared__ float biasS[2048];

    const int kg = (lane >> 4) * 8;
    const int q  = lane & 15;
    const int rb = lane >> 3;
    const int jd = lane & 7;

    const ush* KhT = Kh + (size_t)(b * S) * 1024 + h * DK;
    const ush* KlT = Kl + (size_t)(b * S) * 1024 + h * DK;
    const ush* VtT = Vt + (size_t)(b * 1024 + h * DK) * 2048;

    // ---- mask -> LDS bias (once) ----
    {
        const int t4 = tid * 4;
        int4 mv = *(const int4*)&maskg[b * S + t4];
        biasS[t4 + 0] = mv.x ? 0.f : -1e9f;
        biasS[t4 + 1] = mv.y ? 0.f : -1e9f;
        biasS[t4 + 2] = mv.z ? 0.f : -1e9f;
        biasS[t4 + 3] = mv.w ? 0.f : -1e9f;
    }

    // Q fragments for both groups (named, constant-indexed)
    bf8 qh0[2], ql0[2], qh1[2], ql1[2];
    {
        const int qrow0 = q0 + w * 16 + q;
        const int qrow1 = q0 + 128 + w * 16 + q;
        const ush* p;
        p = Qh + (size_t)(b * S + qrow0) * D + h * DK + kg;
        qh0[0] = *(const bf8*)p; qh0[1] = *(const bf8*)(p + 32);
        p = Ql + (size_t)(b * S + qrow0) * D + h * DK + kg;
        ql0[0] = *(const bf8*)p; ql0[1] = *(const bf8*)(p + 32);
        p = Qh + (size_t)(b * S + qrow1) * D + h * DK + kg;
        qh1[0] = *(const bf8*)p; qh1[1] = *(const bf8*)(p + 32);
        p = Ql + (size_t)(b * S + qrow1) * D + h * DK + kg;
        ql1[0] = *(const bf8*)p; ql1[1] = *(const bf8*)(p + 32);
    }

    // wave w stages rows w*8..w*8+7 of a 64x64 tile with one gl16
    const int rd = w * 8 + rb;
    const int jo = jd ^ (rd & 7);

    auto stKh = [&](int bufi, int k0) {
        gl16(KhT + (size_t)(k0 + rd) * 1024 + jo * 8, &KhsD[bufi][(w * 8) * 64]);
    };
    auto stKl = [&](int bufi, int k0) {
        gl16(KlT + (size_t)(k0 + rd) * 1024 + jo * 8, &KlsD[bufi][(w * 8) * 64]);
    };
    auto stVt = [&](int bufi, int k0) {
        gl16(VtT + (size_t)rd * 2048 + k0 + jo * 8, &VtsD[bufi][(w * 8) * 64]);
    };

    const float scale = 0.125f;                // 1/sqrt(DK)
    float mrow0 = -1e30f, lrow0 = 0.f;
    float mrow1 = -1e30f, lrow1 = 0.f;

    auto computeA = [&](const ush* Khs_, int k0, const bf8* qhg,
                        float& mr, float& lr) {
        f32x4 sacc[4];
#pragma unroll
        for (int st = 0; st < 4; ++st) sacc[st] = (f32x4){0.f, 0.f, 0.f, 0.f};
#pragma unroll
        for (int st = 0; st < 4; ++st) {
            int r = st * 16 + q;
#pragma unroll
            for (int dh = 0; dh < 2; ++dh) {
                bf8 kf = *(const bf8*)&Khs_[r * 64 + ((dh * 32 + kg) ^ ((r & 7) << 3))];
                sacc[st] = __builtin_amdgcn_mfma_f32_16x16x32_bf16(kf, qhg[dh], sacc[st], 0, 0, 0);
            }
        }
        f32x4 bias_r[4];
#pragma unroll
        for (int st = 0; st < 4; ++st)
            bias_r[st] = *(const f32x4*)&biasS[k0 + st * 16 + (lane >> 4) * 4];
        float tmax = -1e30f;
#pragma unroll
        for (int st = 0; st < 4; ++st)
#pragma unroll
            for (int rr = 0; rr < 4; ++rr)
                tmax = fmaxf(tmax, sacc[st][rr] * scale + bias_r[st][rr]);
        tmax = fmaxf(tmax, __shfl_xor(tmax, 16));
        tmax = fmaxf(tmax, __shfl_xor(tmax, 32));
        const float nm = fmaxf(mr, tmax);
        float ts = 0.f;
#pragma unroll
        for (int st = 0; st < 4; ++st)
#pragma unroll
            for (int rr = 0; rr < 4; ++rr)
                ts += __expf(sacc[st][rr] * scale + bias_r[st][rr] - nm);
        ts += __shfl_xor(ts, 16);
        ts += __shfl_xor(ts, 32);
        lr = lr * __expf(mr - nm) + ts;
        mr = nm;
    };

    // ---------------- pass A: 3-deep pipeline, 2 q-groups/iter -------------
    stKh(0, 0); stKh(1, 64);
    __syncthreads();                          // drains prologue + biasS writes
    {
        int cur = 0, nxt = 2;
        for (int kt = 0; kt < 32; ++kt) {
            if (kt + 2 < 32) stKh(nxt, (kt + 2) * 64);
            FENCE();
            computeA(&KhsD[cur][0], kt * 64, qh0, mrow0, lrow0);
            computeA(&KhsD[cur][0], kt * 64, qh1, mrow1, lrow1);
            if (kt < 30) { WAIT_VM(1); } else { WAIT_VM(0); }
            BARRAW(); FENCE();
            cur = (cur == 2) ? 0 : cur + 1;
            nxt = (nxt == 2) ? 0 : nxt + 1;
        }
    }
    const float inv_l0 = 1.f / lrow0;
    const float inv_l1 = 1.f / lrow1;

    // ---------------- pass B: 2-deep, 2 q-groups/iter ----------------------
    f32x4 cacc0[4], cacc1[4];
#pragma unroll
    for (int dt = 0; dt < 4; ++dt) {
        cacc0[dt] = (f32x4){0.f, 0.f, 0.f, 0.f};
        cacc1[dt] = (f32x4){0.f, 0.f, 0.f, 0.f};
    }
    float* attn_bh = attn + (size_t)(b * H + h) * S * S;

    auto computeB = [&](int bsel, int k0, int grow,
                        const bf8* qhg, const bf8* qlg,
                        float mr, float il, f32x4* caccg) {
        const ush* Khs_ = &KhsD[bsel][0];
        const ush* Kls_ = &KlsD[bsel][0];
        const ush* Vts_ = &VtsD[bsel][0];
        f32x4 sacc[4];
#pragma unroll
        for (int st = 0; st < 4; ++st) sacc[st] = (f32x4){0.f, 0.f, 0.f, 0.f};
#pragma unroll
        for (int st = 0; st < 4; ++st) {
            int r = st * 16 + q;
#pragma unroll
            for (int dh = 0; dh < 2; ++dh) {
                bf8 kf = *(const bf8*)&Khs_[r * 64 + ((dh * 32 + kg) ^ ((r & 7) << 3))];
                bf8 lf = *(const bf8*)&Kls_[r * 64 + ((dh * 32 + kg) ^ ((r & 7) << 3))];
                sacc[st] = __builtin_amdgcn_mfma_f32_16x16x32_bf16(kf, qhg[dh], sacc[st], 0, 0, 0);
                sacc[st] = __builtin_amdgcn_mfma_f32_16x16x32_bf16(kf, qlg[dh], sacc[st], 0, 0, 0);
                sacc[st] = __builtin_amdgcn_mfma_f32_16x16x32_bf16(lf, qhg[dh], sacc[st], 0, 0, 0);
            }
        }
#pragma unroll
        for (int st = 0; st < 4; ++st) {
            f32x4 bias_r = *(const f32x4*)&biasS[k0 + st * 16 + (lane >> 4) * 4];
            f32x4 pvv;
#pragma unroll
            for (int rr = 0; rr < 4; ++rr)
                pvv[rr] = __expf(sacc[st][rr] * scale + bias_r[rr] - mr) * il;
            __builtin_nontemporal_store(pvv,
                (f32x4*)&attn_bh[(size_t)(grow + w * 16 + q) * S + k0 + st * 16 + (lane >> 4) * 4]);
#pragma unroll
            for (int rp = 0; rp < 2; ++rp) {
                int key = st * 16 + (lane >> 4) * 4 + rp * 2;
                unsigned int pk = (unsigned int)f2bf_rne(pvv[rp * 2]) |
                                  ((unsigned int)f2bf_rne(pvv[rp * 2 + 1]) << 16);
                *(unsigned int*)&Pus[w][q * 64 + (key ^ ((q & 7) << 3))] = pk;
            }
        }
        bf8 pa[2];
        pa[0] = *(const bf8*)&Pus[w][q * 64 + ((kg)      ^ ((q & 7) << 3))];
        pa[1] = *(const bf8*)&Pus[w][q * 64 + ((32 + kg) ^ ((q & 7) << 3))];
#pragma unroll
        for (int dt = 0; dt < 4; ++dt) {
            int r = dt * 16 + q;
#pragma unroll
            for (int kc2 = 0; kc2 < 2; ++kc2) {
                bf8 vf = *(const bf8*)&Vts_[r * 64 + ((kc2 * 32 + kg) ^ ((r & 7) << 3))];
                caccg[dt] = __builtin_amdgcn_mfma_f32_16x16x32_bf16(pa[kc2], vf, caccg[dt], 0, 0, 0);
            }
        }
    };

    stKh(0, 0); stKl(0, 0); stVt(0, 0);
    FENCE();
    WAIT_VM(0); BARRAW(); FENCE();
    {
        int cur = 0;
        for (int kt = 0; kt < 32; ++kt) {
            if (kt + 1 < 32) {
                const int kN = (kt + 1) * 64;
                stKh(cur ^ 1, kN); stKl(cur ^ 1, kN); stVt(cur ^ 1, kN);
            }
            FENCE();
            computeB(cur, kt * 64, q0,       qh0, ql0, mrow0, inv_l0, cacc0);
            computeB(cur, kt * 64, q0 + 128, qh1, ql1, mrow1, inv_l1, cacc1);
            if (kt + 1 < 32) { WAIT_VM(8); } else { FENCE(); }
            BARRAW(); FENCE();
            cur ^= 1;
        }
    }

    // ctx (bf16, layout [B*S][D] head-major cols), both groups
#pragma unroll
    for (int dt = 0; dt < 4; ++dt)
#pragma unroll
        for (int rr = 0; rr < 4; ++rr) {
            int qq0 = q0 + w * 16 + 4 * (lane >> 4) + rr;
            ctx[(size_t)(b * S + qq0) * D + h * DK + dt * 16 + (lane & 15)] =
                f2bf_rne(cacc0[dt][rr]);
            int qq1 = q0 + 128 + w * 16 + 4 * (lane >> 4) + rr;
            ctx[(size_t)(b * S + qq1) * D + h * DK + dt * 16 + (lane & 15)] =
                f2bf_rne(cacc1[dt][rr]);
        }
}

// ---------------------------------------------------------------------------
extern "C" void kernel_launch(void* const* d_in, const int* in_sizes, int n_in,
                              void* d_out, int out_size, void* d_ws, size_t ws_size,
                              hipStream_t stream)
{
    const float* query = (const float*)d_in[0];
    const float* key   = (const float*)d_in[1];
    const float* value = (const float*)d_in[2];
    const int*   mask  = (const int*)d_in[3];
    const float* w_q   = (const float*)d_in[4];
    const float* w_k   = (const float*)d_in[5];
    const float* w_v   = (const float*)d_in[6];
    const float* w_o   = (const float*)d_in[7];
    const float* b_o   = (const float*)d_in[8];

    float* out  = (float*)d_out;                       // B*S*D fp32
    float* attn = out + (size_t)B * S * D;             // B*H*S*S fp32

    const size_t NE = (size_t)B * S * D;               // 4,194,304 elems
    const size_t WE = (size_t)D * D;                   // 1,048,576 elems

    // d_ws: 6 bf16 buffers = 50.33 MB (proven) + optional woH (+2 MB)
    ush* Qh = (ush*)d_ws;
    ush* Ql = Qh + NE;
    ush* Kh = Ql + NE;
    ush* Kl = Kh + NE;
    ush* Vt = Kl + NE;                                 // [B][D][S] bf16
    ush* Cb = Vt + NE;                                 // ctx bf16
    ush* woWS = Cb + NE;                               // w_o hi (gated)

    const bool woInWs = ws_size >= (size_t)(6 * NE + WE) * 2;

    // conv staging in d_out's attn region (537 MB): dead before attn_mfma5,
    // which then overwrites every byte.
    ush* qXh = (ush*)attn;
    ush* qXl = qXh + NE;
    ush* kXh = qXl + NE;
    ush* kXl = kXh + NE;
    ush* vXh = kXl + NE;
    ush* wqH = vXh + NE;
    ush* wqL = wqH + WE;
    ush* wkH = wqL + WE;
    ush* wkL = wkH + WE;
    ush* wvH = wkL + WE;

    ush* woH = woInWs ? woWS : Qh;   // fallback: Qh region, converted post-attn

    const dim3 blk(256);
    const dim3 pgrid(D / 64, (B * S) / 128, 3);        // (16, 32, 3) merged QKV
    const dim3 ogrid(D / 64, (B * S) / 128);           // (16, 32) out
    const dim3 agrid(S / 256, H, B);                   // (8, 16, 2) = 256 blocks

    const int nbX = (int)(NE / 8 / 256);               // 2048
    const int nbW = (int)(WE / 8 / 256);               // 512

    // merged pre-convert (1 launch; 7 segments when w_o fits in d_ws)
    const int nseg = 3 * nbX + (woInWs ? 4 : 3) * nbW;
    conv_sev_k<<<dim3(nseg), blk, 0, stream>>>(
        query, qXh, qXl, w_q, wqH, wqL,
        key,   kXh, kXl, w_k, wkH, wkL,
        value, vXh, w_v, wvH, w_o, woH, nbX, nbW);

    // merged Q/K/V projections (1 launch, 2 blocks/CU + counted vmcnt)
    gemm_proj3<<<pgrid, blk, 0, stream>>>(
        qXh, qXl, wqH, wqL, Qh, Ql,
        kXh, kXl, wkH, wkL, Kh, Kl,
        vXh, wvH, Vt);

    // attention (overwrites the staging region with the real attn output)
    attn_mfma5<<<agrid, dim3(512), 0, stream>>>(Qh, Ql, Kh, Kl, Vt, mask, attn, Cb);

    // out = ctx @ w_o^T + b_o
    if (!woInWs)
        conv_hi_k<<<dim3(nbW), blk, 0, stream>>>(w_o, woH);
    gemm_outk<<<ogrid, blk, 0, stream>>>(Cb, woH, b_o, out);
}

// Round 13
// 313.622 us; speedup vs baseline: 1.0722x; 1.0722x over previous
//
#include <hip/hip_runtime.h>
#include <hip/hip_bf16.h>
#include <math.h>

#define B 2
#define S 2048
#define D 1024
#define H 16
#define DK 64

typedef __attribute__((ext_vector_type(8))) short bf8;            // 8 bf16 (MFMA frag)
typedef __attribute__((ext_vector_type(8))) unsigned short u16x8;
typedef __attribute__((ext_vector_type(4))) unsigned short u16x4;
typedef __attribute__((ext_vector_type(4))) float f32x4;
typedef unsigned short ush;

__device__ __forceinline__ float bf2f(ush u) {
    union { unsigned int i; float f; } v; v.i = ((unsigned int)u) << 16; return v.f;
}
__device__ __forceinline__ ush f2bf_rne(float x) {
    __hip_bfloat16 h = __float2bfloat16(x);
    union { __hip_bfloat16 h; ush u; } v; v.h = h; return v.u;
}
__device__ __forceinline__ ush f2bf_trunc(float x) {
    union { float f; unsigned int i; } v; v.f = x; return (ush)(v.i >> 16);
}

// async global->LDS, 16B per lane. LDS dest = wave-uniform base + lane*16.
__device__ __forceinline__ void gl16(const void* g, void* l) {
    __builtin_amdgcn_global_load_lds(
        (const __attribute__((address_space(1))) void*)g,
        (__attribute__((address_space(3))) void*)l, 16, 0, 0);
}

#define FENCE()    asm volatile("" ::: "memory")
#define WAIT_VM(N) asm volatile("s_waitcnt vmcnt(" #N ")" ::: "memory")
#define BARRAW()   __builtin_amdgcn_s_barrier()

// ---------------------------------------------------------------------------
// Merged pre-convert: up to 7 segments
// (query/w_q/key/w_k split; value/w_v hi-only; optional w_o hi-only)
// ---------------------------------------------------------------------------
__global__ __launch_bounds__(256) void conv_sev_k(
    const float* __restrict__ q,  ush* __restrict__ qh,  ush* __restrict__ qlo,
    const float* __restrict__ wq, ush* __restrict__ wqh, ush* __restrict__ wql,
    const float* __restrict__ k,  ush* __restrict__ kh,  ush* __restrict__ klo,
    const float* __restrict__ wk, ush* __restrict__ wkh, ush* __restrict__ wkl,
    const float* __restrict__ v,  ush* __restrict__ vh,
    const float* __restrict__ wv, ush* __restrict__ wvh,
    const float* __restrict__ wo, ush* __restrict__ woh,
    int nbX, int nbW)
{
    int bx = blockIdx.x;
    const float* src; ush* oh; ush* ol;
    if (bx < nbX) { src = q; oh = qh; ol = qlo; }
    else { bx -= nbX;
      if (bx < nbW) { src = wq; oh = wqh; ol = wql; }
      else { bx -= nbW;
        if (bx < nbX) { src = k; oh = kh; ol = klo; }
        else { bx -= nbX;
          if (bx < nbW) { src = wk; oh = wkh; ol = wkl; }
          else { bx -= nbW;
            if (bx < nbX) { src = v; oh = vh; ol = nullptr; }
            else { bx -= nbX;
              if (bx < nbW) { src = wv; oh = wvh; ol = nullptr; }
              else { bx -= nbW; src = wo; oh = woh; ol = nullptr; }
            } } } } }
    const size_t t = (size_t)bx * 256 + threadIdx.x;

    const float4* s4 = (const float4*)src + t * 2;
    float4 a = s4[0], c = s4[1];
    float vv[8] = {a.x, a.y, a.z, a.w, c.x, c.y, c.z, c.w};
    u16x8 hi;
#pragma unroll
    for (int j = 0; j < 8; ++j) hi[j] = f2bf_trunc(vv[j]);
    *(u16x8*)&oh[t * 8] = hi;
    if (ol) {
        u16x8 lo;
#pragma unroll
        for (int j = 0; j < 8; ++j) lo[j] = f2bf_rne(vv[j] - bf2f(hi[j]));
        *(u16x8*)&ol[t * 8] = lo;
    }
}

// single-tensor hi-only convert (fallback path for w_o)
__global__ __launch_bounds__(256) void conv_hi_k(
    const float* __restrict__ X, ush* __restrict__ Oh)
{
    const size_t t = (size_t)blockIdx.x * 256 + threadIdx.x;
    const float4* s4 = (const float4*)X + t * 2;
    float4 a = s4[0], c = s4[1];
    float v[8] = {a.x, a.y, a.z, a.w, c.x, c.y, c.z, c.w};
    u16x8 hi;
#pragma unroll
    for (int j = 0; j < 8; ++j) hi[j] = f2bf_trunc(v[j]);
    *(u16x8*)&Oh[t * 8] = hi;
}

// ---------------------------------------------------------------------------
// MFMA GEMM body v2 (round-10 proven): 128n x 64m tile, 256 thr / 4 waves,
// 3 LDS buffers (72 KB -> 2 blocks/CU), 2-deep counted-vmcnt (WAIT_VM(6)).
// EPI 0: fp32+bias(nt)  EPI 1: hi/lo pair  EPI 2: transposed bf16 [B][D][S]
// ---------------------------------------------------------------------------
template<bool SPLIT, int EPI>
__device__ __forceinline__ void gemm_body2(
    const ush* __restrict__ Xh, const ush* __restrict__ Xl,
    const ush* __restrict__ Wh, const ush* __restrict__ Wl,
    const float* __restrict__ bias, void* __restrict__ Y0v, void* __restrict__ Y1v,
    ush* BufS)
{
    const int tid  = threadIdx.x;
    const int lane = tid & 63;
    const int w    = tid >> 6;                 // 0..3
    const int wn   = w >> 1, wm = w & 1;
    const int m0   = blockIdx.x * 64;
    const int n0   = blockIdx.y * 128;

    f32x4 acc[4][2];
#pragma unroll
    for (int s = 0; s < 4; ++s)
#pragma unroll
        for (int t = 0; t < 2; ++t) acc[s][t] = (f32x4){0.f, 0.f, 0.f, 0.f};

    const int kg = (lane >> 4) * 8;
    const int rb = lane >> 3;                  // 0..7
    const int jd = lane & 7;
    const int kS = SPLIT ? 32 : 16;

    auto stage = [&](ush* buf, int ks) {
#pragma unroll
        for (int i = 0; i < 6; ++i) {
            int rd = w * 48 + i * 8 + rb;      // 0..191
            int jo = jd ^ (rd & 7);
            const ush* src;
            if (rd < 128) {                    // X row
                if (SPLIT)
                    src = (jo < 4) ? Xh + (size_t)(n0 + rd) * 1024 + ks * 32 + jo * 8
                                   : Xl + (size_t)(n0 + rd) * 1024 + ks * 32 + (jo - 4) * 8;
                else
                    src = Xh + (size_t)(n0 + rd) * 1024 + ks * 64 + jo * 8;
            } else {                           // W row
                int rw = rd - 128;
                if (SPLIT)
                    src = (jo < 4) ? Wh + (size_t)(m0 + rw) * 1024 + ks * 32 + jo * 8
                                   : Wl + (size_t)(m0 + rw) * 1024 + ks * 32 + (jo - 4) * 8;
                else
                    src = Wh + (size_t)(m0 + rw) * 1024 + ks * 64 + jo * 8;
            }
            gl16(src, &buf[(w * 48 + i * 8) * 64]);
        }
    };

    auto step = [&](const ush* buf) {
        bf8 a0[4], a1[4], b0[2], b1[2];
#pragma unroll
        for (int s = 0; s < 4; ++s) {
            int r = wn * 64 + s * 16 + (lane & 15);
            a0[s] = *(const bf8*)&buf[r * 64 + (kg ^ ((r & 7) << 3))];
            a1[s] = *(const bf8*)&buf[r * 64 + ((32 + kg) ^ ((r & 7) << 3))];
        }
#pragma unroll
        for (int t = 0; t < 2; ++t) {
            int r = wm * 32 + t * 16 + (lane & 15);
            b0[t] = *(const bf8*)&buf[(128 + r) * 64 + (kg ^ ((r & 7) << 3))];
            b1[t] = *(const bf8*)&buf[(128 + r) * 64 + ((32 + kg) ^ ((r & 7) << 3))];
        }
#pragma unroll
        for (int s = 0; s < 4; ++s)
#pragma unroll
            for (int t = 0; t < 2; ++t) {
                acc[s][t] = __builtin_amdgcn_mfma_f32_16x16x32_bf16(a0[s], b0[t], acc[s][t], 0, 0, 0);
                if (SPLIT) {
                    acc[s][t] = __builtin_amdgcn_mfma_f32_16x16x32_bf16(a0[s], b1[t], acc[s][t], 0, 0, 0);
                    acc[s][t] = __builtin_amdgcn_mfma_f32_16x16x32_bf16(a1[s], b0[t], acc[s][t], 0, 0, 0);
                } else {
                    acc[s][t] = __builtin_amdgcn_mfma_f32_16x16x32_bf16(a1[s], b1[t], acc[s][t], 0, 0, 0);
                }
            }
    };

    stage(&BufS[0 * 12288], 0);
    stage(&BufS[1 * 12288], 1);
    FENCE();
    WAIT_VM(6); BARRAW(); FENCE();

    for (int kt = 0; kt < kS; ++kt) {
        const int pf = kt + 2;
        if (pf < kS) { stage(&BufS[(pf % 3) * 12288], pf); FENCE(); }
        step(&BufS[(kt % 3) * 12288]);
        if (kt + 2 < kS)      { WAIT_VM(6); }
        else if (kt + 1 < kS) { WAIT_VM(0); }
        BARRAW(); FENCE();
    }

#pragma unroll
    for (int s = 0; s < 4; ++s)
#pragma unroll
        for (int t = 0; t < 2; ++t) {
            const int nb = n0 + wn * 64 + 16 * s + 4 * (lane >> 4);
            const int m  = m0 + wm * 32 + 16 * t + (lane & 15);
            if (EPI == 0) {
                float* Y = (float*)Y0v;
                const float bb = bias[m];
#pragma unroll
                for (int r = 0; r < 4; ++r)
                    __builtin_nontemporal_store(acc[s][t][r] + bb,
                                                &Y[(size_t)(nb + r) * 1024 + m]);
            } else if (EPI == 1) {
                ush* Yh = (ush*)Y0v;
                ush* Yl = (ush*)Y1v;
#pragma unroll
                for (int r = 0; r < 4; ++r) {
                    float v = acc[s][t][r];
                    ush hi = f2bf_trunc(v);
                    Yh[(size_t)(nb + r) * 1024 + m] = hi;
                    Yl[(size_t)(nb + r) * 1024 + m] = f2bf_rne(v - bf2f(hi));
                }
            } else {
                ush* Vt = (ush*)Y0v;
                u16x4 pk;
#pragma unroll
                for (int r = 0; r < 4; ++r) pk[r] = f2bf_rne(acc[s][t][r]);
                size_t addr = ((size_t)(nb >> 11) * 1024 + m) * 2048 + (nb & 2047);
                *(u16x4*)&Vt[addr] = pk;
            }
        }
}

// merged Q/K/V projection launch: z selects the GEMM
__global__ __launch_bounds__(256) void gemm_proj3(
    const ush* __restrict__ qXh, const ush* __restrict__ qXl,
    const ush* __restrict__ wqH, const ush* __restrict__ wqL,
    ush* __restrict__ Qh, ush* __restrict__ Ql,
    const ush* __restrict__ kXh, const ush* __restrict__ kXl,
    const ush* __restrict__ wkH, const ush* __restrict__ wkL,
    ush* __restrict__ Kh, ush* __restrict__ Kl,
    const ush* __restrict__ vXh, const ush* __restrict__ wvH,
    ush* __restrict__ Vt)
{
    __shared__ __align__(16) ush BufS[3 * 192 * 64];   // 72 KB
    const int z = blockIdx.z;
    if (z == 0)      gemm_body2<true, 1>(qXh, qXl, wqH, wqL, nullptr, Qh, Ql, BufS);
    else if (z == 1) gemm_body2<true, 1>(kXh, kXl, wkH, wkL, nullptr, Kh, Kl, BufS);
    else             gemm_body2<false, 2>(vXh, nullptr, wvH, nullptr, nullptr, Vt, nullptr, BufS);
}

// out-projection: fp32 + bias epilogue (nontemporal)
__global__ __launch_bounds__(256) void gemm_outk(
    const ush* __restrict__ Xh, const ush* __restrict__ Wh,
    const float* __restrict__ bias, float* __restrict__ Y)
{
    __shared__ __align__(16) ush BufS[3 * 192 * 64];   // 72 KB
    gemm_body2<false, 0>(Xh, nullptr, Wh, nullptr, bias, Y, nullptr, BufS);
}

// ---------------------------------------------------------------------------
// Attention per (b, h, 128-q-tile). 512 thr / 8 waves, wave owns 16 q rows.
// XCD-swizzled block id. Mask staged to LDS once. Pass A: 3-deep Kh pipeline,
// vmcnt(1). Pass B: 2-deep (Kh,Kl,Vt), vmcnt(4) leaves the attn stores in
// flight; attn stores NONTEMPORAL to keep K/V L2-resident. [round-10 optimum]
// ---------------------------------------------------------------------------
__global__ __launch_bounds__(512) void attn_mfma4(
    const ush* __restrict__ Qh, const ush* __restrict__ Ql,
    const ush* __restrict__ Kh, const ush* __restrict__ Kl,
    const ush* __restrict__ Vt, const int* __restrict__ maskg,
    float* __restrict__ attn, ush* __restrict__ ctx)
{
    const int tid  = threadIdx.x;
    const int lane = tid & 63;
    const int w    = tid >> 6;                 // 0..7
    const int lid  = blockIdx.x + (blockIdx.y << 4) + (blockIdx.z << 8);
    const int swz  = ((lid & 7) << 6) | (lid >> 3);   // XCD groups 4 heads
    const int qt = swz & 15, h = (swz >> 4) & 15, b = swz >> 8;
    const int q0 = qt * 128;

    __shared__ __align__(16) ush KhsD[3][4096];
    __shared__ __align__(16) ush KlsD[2][4096];
    __shared__ __align__(16) ush VtsD[2][4096];
    __shared__ __align__(16) ush Pus[8][1024];
    __shared__ float biasS[2048];

    const int kg = (lane >> 4) * 8;
    const int q  = lane & 15;
    const int qrow = q0 + w * 16 + q;
    const int rb = lane >> 3;
    const int jd = lane & 7;

    const ush* KhT = Kh + (size_t)(b * S) * 1024 + h * DK;
    const ush* KlT = Kl + (size_t)(b * S) * 1024 + h * DK;
    const ush* VtT = Vt + (size_t)(b * 1024 + h * DK) * 2048;

    // ---- mask -> LDS bias (once) ----
    {
        const int t4 = tid * 4;
        int4 mv = *(const int4*)&maskg[b * S + t4];
        biasS[t4 + 0] = mv.x ? 0.f : -1e9f;
        biasS[t4 + 1] = mv.y ? 0.f : -1e9f;
        biasS[t4 + 2] = mv.z ? 0.f : -1e9f;
        biasS[t4 + 3] = mv.w ? 0.f : -1e9f;
    }

    bf8 qh[2], ql[2];
    {
        const ush* p1 = Qh + (size_t)(b * S + qrow) * D + h * DK + kg;
        qh[0] = *(const bf8*)p1; qh[1] = *(const bf8*)(p1 + 32);
        const ush* p2 = Ql + (size_t)(b * S + qrow) * D + h * DK + kg;
        ql[0] = *(const bf8*)p2; ql[1] = *(const bf8*)(p2 + 32);
    }

    // wave w stages rows w*8..w*8+7 of a 64x64 tile with one gl16
    const int rd = w * 8 + rb;
    const int jo = jd ^ (rd & 7);

    auto stKh = [&](int bufi, int k0) {
        gl16(KhT + (size_t)(k0 + rd) * 1024 + jo * 8, &KhsD[bufi][(w * 8) * 64]);
    };
    auto stKl = [&](int bufi, int k0) {
        gl16(KlT + (size_t)(k0 + rd) * 1024 + jo * 8, &KlsD[bufi][(w * 8) * 64]);
    };
    auto stVt = [&](int bufi, int k0) {
        gl16(VtT + (size_t)rd * 2048 + k0 + jo * 8, &VtsD[bufi][(w * 8) * 64]);
    };

    const float scale = 0.125f;                // 1/sqrt(DK)
    float mrow = -1e30f, lrow = 0.f;

    auto computeA = [&](const ush* Khs_, int k0) {
        f32x4 sacc[4];
#pragma unroll
        for (int st = 0; st < 4; ++st) sacc[st] = (f32x4){0.f, 0.f, 0.f, 0.f};
#pragma unroll
        for (int st = 0; st < 4; ++st) {
            int r = st * 16 + q;
#pragma unroll
            for (int dh = 0; dh < 2; ++dh) {
                bf8 kf = *(const bf8*)&Khs_[r * 64 + ((dh * 32 + kg) ^ ((r & 7) << 3))];
                sacc[st] = __builtin_amdgcn_mfma_f32_16x16x32_bf16(kf, qh[dh], sacc[st], 0, 0, 0);
            }
        }
        f32x4 bias_r[4];
#pragma unroll
        for (int st = 0; st < 4; ++st)
            bias_r[st] = *(const f32x4*)&biasS[k0 + st * 16 + (lane >> 4) * 4];
        float tmax = -1e30f;
#pragma unroll
        for (int st = 0; st < 4; ++st)
#pragma unroll
            for (int rr = 0; rr < 4; ++rr)
                tmax = fmaxf(tmax, sacc[st][rr] * scale + bias_r[st][rr]);
        tmax = fmaxf(tmax, __shfl_xor(tmax, 16));
        tmax = fmaxf(tmax, __shfl_xor(tmax, 32));
        const float nm = fmaxf(mrow, tmax);
        float ts = 0.f;
#pragma unroll
        for (int st = 0; st < 4; ++st)
#pragma unroll
            for (int rr = 0; rr < 4; ++rr)
                ts += __expf(sacc[st][rr] * scale + bias_r[st][rr] - nm);
        ts += __shfl_xor(ts, 16);
        ts += __shfl_xor(ts, 32);
        lrow = lrow * __expf(mrow - nm) + ts;
        mrow = nm;
    };

    // ---------------- pass A: 3-deep pipeline ----------------
    stKh(0, 0); stKh(1, 64);
    __syncthreads();                          // drains prologue + biasS writes
    {
        int cur = 0, nxt = 2;
        for (int kt = 0; kt < 32; ++kt) {
            if (kt + 2 < 32) stKh(nxt, (kt + 2) * 64);
            FENCE();
            computeA(&KhsD[cur][0], kt * 64);
            if (kt < 30) { WAIT_VM(1); } else { WAIT_VM(0); }
            BARRAW(); FENCE();
            cur = (cur == 2) ? 0 : cur + 1;
            nxt = (nxt == 2) ? 0 : nxt + 1;
        }
    }
    const float inv_l = 1.f / lrow;

    // ---------------- pass B: 2-deep, stores stay in flight ----------------
    f32x4 cacc[4];
#pragma unroll
    for (int dt = 0; dt < 4; ++dt) cacc[dt] = (f32x4){0.f, 0.f, 0.f, 0.f};
    float* attn_bh = attn + (size_t)(b * H + h) * S * S;

    auto computeB = [&](int bsel, int k0) {
        const ush* Khs_ = &KhsD[bsel][0];
        const ush* Kls_ = &KlsD[bsel][0];
        const ush* Vts_ = &VtsD[bsel][0];
        f32x4 sacc[4];
#pragma unroll
        for (int st = 0; st < 4; ++st) sacc[st] = (f32x4){0.f, 0.f, 0.f, 0.f};
#pragma unroll
        for (int st = 0; st < 4; ++st) {
            int r = st * 16 + q;
#pragma unroll
            for (int dh = 0; dh < 2; ++dh) {
                bf8 kf = *(const bf8*)&Khs_[r * 64 + ((dh * 32 + kg) ^ ((r & 7) << 3))];
                bf8 lf = *(const bf8*)&Kls_[r * 64 + ((dh * 32 + kg) ^ ((r & 7) << 3))];
                sacc[st] = __builtin_amdgcn_mfma_f32_16x16x32_bf16(kf, qh[dh], sacc[st], 0, 0, 0);
                sacc[st] = __builtin_amdgcn_mfma_f32_16x16x32_bf16(kf, ql[dh], sacc[st], 0, 0, 0);
                sacc[st] = __builtin_amdgcn_mfma_f32_16x16x32_bf16(lf, qh[dh], sacc[st], 0, 0, 0);
            }
        }
#pragma unroll
        for (int st = 0; st < 4; ++st) {
            f32x4 bias_r = *(const f32x4*)&biasS[k0 + st * 16 + (lane >> 4) * 4];
            f32x4 pvv;
#pragma unroll
            for (int rr = 0; rr < 4; ++rr)
                pvv[rr] = __expf(sacc[st][rr] * scale + bias_r[rr] - mrow) * inv_l;
            __builtin_nontemporal_store(pvv,
                (f32x4*)&attn_bh[(size_t)(q0 + w * 16 + q) * S + k0 + st * 16 + (lane >> 4) * 4]);
#pragma unroll
            for (int rp = 0; rp < 2; ++rp) {
                int key = st * 16 + (lane >> 4) * 4 + rp * 2;
                unsigned int pk = (unsigned int)f2bf_rne(pvv[rp * 2]) |
                                  ((unsigned int)f2bf_rne(pvv[rp * 2 + 1]) << 16);
                *(unsigned int*)&Pus[w][q * 64 + (key ^ ((q & 7) << 3))] = pk;
            }
        }
        bf8 pa[2];
        pa[0] = *(const bf8*)&Pus[w][q * 64 + ((kg)      ^ ((q & 7) << 3))];
        pa[1] = *(const bf8*)&Pus[w][q * 64 + ((32 + kg) ^ ((q & 7) << 3))];
#pragma unroll
        for (int dt = 0; dt < 4; ++dt) {
            int r = dt * 16 + q;
#pragma unroll
            for (int kc2 = 0; kc2 < 2; ++kc2) {
                bf8 vf = *(const bf8*)&Vts_[r * 64 + ((kc2 * 32 + kg) ^ ((r & 7) << 3))];
                cacc[dt] = __builtin_amdgcn_mfma_f32_16x16x32_bf16(pa[kc2], vf, cacc[dt], 0, 0, 0);
            }
        }
    };

    stKh(0, 0); stKl(0, 0); stVt(0, 0);
    FENCE();
    WAIT_VM(0); BARRAW(); FENCE();
    {
        int cur = 0;
        for (int kt = 0; kt < 32; ++kt) {
            if (kt + 1 < 32) {
                const int kN = (kt + 1) * 64;
                stKh(cur ^ 1, kN); stKl(cur ^ 1, kN); stVt(cur ^ 1, kN);
            }
            FENCE();
            computeB(cur, kt * 64);
            if (kt + 1 < 32) { WAIT_VM(4); } else { FENCE(); }
            BARRAW(); FENCE();
            cur ^= 1;
        }
    }

    // ctx (bf16, layout [B*S][D] head-major cols)
#pragma unroll
    for (int dt = 0; dt < 4; ++dt)
#pragma unroll
        for (int rr = 0; rr < 4; ++rr) {
            int qq = q0 + w * 16 + 4 * (lane >> 4) + rr;
            ctx[(size_t)(b * S + qq) * D + h * DK + dt * 16 + (lane & 15)] =
                f2bf_rne(cacc[dt][rr]);
        }
}

// ---------------------------------------------------------------------------
extern "C" void kernel_launch(void* const* d_in, const int* in_sizes, int n_in,
                              void* d_out, int out_size, void* d_ws, size_t ws_size,
                              hipStream_t stream)
{
    const float* query = (const float*)d_in[0];
    const float* key   = (const float*)d_in[1];
    const float* value = (const float*)d_in[2];
    const int*   mask  = (const int*)d_in[3];
    const float* w_q   = (const float*)d_in[4];
    const float* w_k   = (const float*)d_in[5];
    const float* w_v   = (const float*)d_in[6];
    const float* w_o   = (const float*)d_in[7];
    const float* b_o   = (const float*)d_in[8];

    float* out  = (float*)d_out;                       // B*S*D fp32
    float* attn = out + (size_t)B * S * D;             // B*H*S*S fp32

    const size_t NE = (size_t)B * S * D;               // 4,194,304 elems
    const size_t WE = (size_t)D * D;                   // 1,048,576 elems

    // d_ws: 6 bf16 buffers = 50.33 MB (proven) + optional woH (+2 MB;
    // ws >= 71 MB established by round-6 A/B vs rounds 3-5).
    ush* Qh = (ush*)d_ws;
    ush* Ql = Qh + NE;
    ush* Kh = Ql + NE;
    ush* Kl = Kh + NE;
    ush* Vt = Kl + NE;                                 // [B][D][S] bf16
    ush* Cb = Vt + NE;                                 // ctx bf16
    ush* woWS = Cb + NE;                               // w_o hi (gated)

    const bool woInWs = ws_size >= (size_t)(6 * NE + WE) * 2;

    // conv staging in d_out's attn region (537 MB): dead before attn_mfma4,
    // which then overwrites every byte.
    ush* qXh = (ush*)attn;
    ush* qXl = qXh + NE;
    ush* kXh = qXl + NE;
    ush* kXl = kXh + NE;
    ush* vXh = kXl + NE;
    ush* wqH = vXh + NE;
    ush* wqL = wqH + WE;
    ush* wkH = wqL + WE;
    ush* wkL = wkH + WE;
    ush* wvH = wkL + WE;

    ush* woH = woInWs ? woWS : Qh;   // fallback: Qh region, converted post-attn

    const dim3 blk(256);
    const dim3 pgrid(D / 64, (B * S) / 128, 3);        // (16, 32, 3) merged QKV
    const dim3 ogrid(D / 64, (B * S) / 128);           // (16, 32) out
    const dim3 agrid(S / 128, H, B);                   // (16, 16, 2)

    const int nbX = (int)(NE / 8 / 256);               // 2048
    const int nbW = (int)(WE / 8 / 256);               // 512

    // merged pre-convert (1 launch; 7 segments when w_o fits in d_ws)
    const int nseg = 3 * nbX + (woInWs ? 4 : 3) * nbW;
    conv_sev_k<<<dim3(nseg), blk, 0, stream>>>(
        query, qXh, qXl, w_q, wqH, wqL,
        key,   kXh, kXl, w_k, wkH, wkL,
        value, vXh, w_v, wvH, w_o, woH, nbX, nbW);

    // merged Q/K/V projections (1 launch, 2 blocks/CU + counted vmcnt)
    gemm_proj3<<<pgrid, blk, 0, stream>>>(
        qXh, qXl, wqH, wqL, Qh, Ql,
        kXh, kXl, wkH, wkL, Kh, Kl,
        vXh, wvH, Vt);

    // attention (overwrites the staging region with the real attn output)
    attn_mfma4<<<agrid, dim3(512), 0, stream>>>(Qh, Ql, Kh, Kl, Vt, mask, attn, Cb);

    // out = ctx @ w_o^T + b_o
    if (!woInWs)
        conv_hi_k<<<dim3(nbW), blk, 0, stream>>>(w_o, woH);
    gemm_outk<<<ogrid, blk, 0, stream>>>(Cb, woH, b_o, out);
}